// Round 4
// baseline (1036.666 us; speedup 1.0000x reference)
//
#include <hip/hip_runtime.h>
#include <stdint.h>

typedef unsigned short u16;
typedef __bf16 bf16x8 __attribute__((ext_vector_type(8)));
typedef float f32x4 __attribute__((ext_vector_type(4)));

__device__ inline u16 f32_to_bf16(float f) {
  union { float f; uint32_t u; } v; v.f = f;
  uint32_t u = v.u;
  u += 0x7FFF + ((u >> 16) & 1);   // round-to-nearest-even
  return (u16)(u >> 16);
}

__device__ inline void async_load16(const void* g, void* l) {
  __builtin_amdgcn_global_load_lds(
      (const __attribute__((address_space(1))) void*)g,
      (__attribute__((address_space(3))) void*)l, 16, 0, 0);
}

#define BM 128
#define BN 128
#define BK 64

// C = A @ B^T (A,B bf16).  A: [M,K] (lda), B: [N,K] (ldb), C: [M,N] (ldc).
// epi: 2 = +bias, bf16 store; 3 = +bias, FP32 store. bias may be nullptr.
// Optional batching over blockIdx.z: element offsets zb*O + zh*I with
// zb = z>>4, zh = z&15 (covers both linear and (b,h)-split layouts).
// R4: reverted to the R0 128x128 2-phase structure (best measured: 963 TF
// on the qkv GEMM; R1-R3 8-phase attempts all <= this).
// LDS XOR chunk swizzle (slot c holds global chunk c^(row&7)) -> 0 bank
// conflicts. Grid swizzle: 8-n-tile supergroups cut L2 footprint ~2x.
__global__ __launch_bounds__(256, 2) void gemm_bt(
    const u16* __restrict__ A, const u16* __restrict__ B, void* __restrict__ Cp,
    const float* __restrict__ bias, int K, int lda, int ldb, int ldc, int epi,
    int64_t aO, int64_t aI, int64_t bO, int64_t bI, int64_t cO, int64_t cI)
{
  __shared__ u16 As[BM * BK];   // 16 KB
  __shared__ u16 Bs[BN * BK];   // 16 KB

  const int t = threadIdx.x;
  const int lane = t & 63;
  const int wave = t >> 6;

  const int zb = blockIdx.z >> 4, zh = blockIdx.z & 15;
  A += zb * aO + zh * aI;
  B += zb * bO + zh * bI;
  u16*   Cb = (u16*)Cp + zb * cO + zh * cI;
  float* Cf = (float*)Cp + zb * cO + zh * cI;

  int bx = blockIdx.x, by = blockIdx.y;
  if ((gridDim.x & 7) == 0) {          // L2 super-tile swizzle
    int bid = by * gridDim.x + bx;
    int tig = gridDim.y << 3;
    int g = bid / tig;
    int l = bid - g * tig;
    bx = (g << 3) + (l & 7);
    by = l >> 3;
  }
  const int m0 = by * BM;
  const int n0 = bx * BN;
  const int wm = (wave >> 1) * 64;
  const int wn = (wave & 1) * 64;

  // staging: thread t owns slot (row=t>>3, chunk=t&7) of rows r, r+32, r+64, r+96
  const int sr = t >> 3;
  const int sc = t & 7;
  const int csw = sc ^ (sr & 7);
  const u16* ga = A + (size_t)(m0 + sr) * lda + csw * 8;
  const u16* gb = B + (size_t)(n0 + sr) * ldb + csw * 8;
  const size_t a32 = (size_t)32 * lda;
  const size_t b32 = (size_t)32 * ldb;
  u16* lA = As + t * 8;
  u16* lB = Bs + t * 8;

  f32x4 acc[4][4] = {};

  const int fr = lane & 15;
  const int q  = lane >> 4;
  const int xk = fr & 7;

  for (int kt = 0; kt < K; kt += BK) {
    async_load16(ga,            lA);
    async_load16(ga +     a32,  lA + 2048);
    async_load16(ga + 2 * a32,  lA + 4096);
    async_load16(ga + 3 * a32,  lA + 6144);
    async_load16(gb,            lB);
    async_load16(gb +     b32,  lB + 2048);
    async_load16(gb + 2 * b32,  lB + 4096);
    async_load16(gb + 3 * b32,  lB + 6144);
    ga += BK; gb += BK;
    __syncthreads();

#pragma unroll
    for (int s = 0; s < 2; ++s) {
      const int ch = (((s << 2) | q) ^ xk) << 3;
      bf16x8 af[4], bfrag[4];
#pragma unroll
      for (int i = 0; i < 4; ++i)
        af[i] = *(const bf16x8*)(As + (wm + i * 16 + fr) * BK + ch);
#pragma unroll
      for (int j = 0; j < 4; ++j)
        bfrag[j] = *(const bf16x8*)(Bs + (wn + j * 16 + fr) * BK + ch);
#pragma unroll
      for (int i = 0; i < 4; ++i)
#pragma unroll
        for (int j = 0; j < 4; ++j)
          acc[i][j] = __builtin_amdgcn_mfma_f32_16x16x32_bf16(af[i], bfrag[j], acc[i][j], 0, 0, 0);
    }
    __syncthreads();
  }

  // C/D layout: row = (lane>>4)*4 + r, col = lane&15
  const int er = (lane >> 4) * 4;
  const int ec = lane & 15;
#pragma unroll
  for (int i = 0; i < 4; ++i) {
#pragma unroll
    for (int j = 0; j < 4; ++j) {
      const int n = n0 + wn + j * 16 + ec;
      const float bv = bias ? bias[n] : 0.0f;
#pragma unroll
      for (int r = 0; r < 4; ++r) {
        const int m = m0 + wm + i * 16 + er + r;
        float v = acc[i][j][r] + bv;
        if (epi == 3) Cf[(size_t)m * ldc + n] = v;
        else          Cb[(size_t)m * ldc + n] = f32_to_bf16(v);
      }
    }
  }
}

// Fused attention, R4: Y = P @ W2t with W2t = (V@V)^T precomputed per head.
// Per workgroup = (head, quarter qh: 64 q-rows).
// Phase 1: S = Q@K^T, scale+causal+relu -> Ps (LDS, [64][264] bf16).
//   Causal: quarter qh only needs keys < (qh+1)*64 -> stage only 2*(qh+1)
//   K row-groups; waves with fully-masked strips (wave > qh) skip MFMA.
//   Garbage in unstaged KVs rows only reaches masked acc entries (epilogue
//   writes 0 there; NaN-safe since v>0.f is false for NaN).
// Phase 2: Y = Ps @ W2t over kt < (qh+1)*64 only (P is 0 beyond) -> y.
__global__ __launch_bounds__(256, 2) void attn_fused(
    const u16* __restrict__ qkv, const u16* __restrict__ w2,
    u16* __restrict__ y)
{
  const int head = blockIdx.x >> 2;    // 0..255
  const int qh   = blockIdx.x & 3;     // q quarter
  const int b    = head >> 4;
  const int h    = head & 15;
  const int C3 = 12288;

  __shared__ u16 Ps[64 * 264];   // P, pad 264 (row 528 B: +4 banks/row, 16B-aligned)
  __shared__ u16 Qs[64 * 64];    // 8 KB
  __shared__ u16 KVs[256 * 64];  // 32 KB (K-tile, then W2t-tiles)

  const int t = threadIdx.x;
  const int lane = t & 63;
  const int wave = t >> 6;       // wave owns n-cols [wave*64, wave*64+64)
  const int wn = wave * 64;

  const int sr = t >> 3;
  const int sc = t & 7;
  const int csw = sc ^ (sr & 7);

  const u16* qbase  = qkv + (size_t)(b * 256 + qh * 64 + sr) * C3 + h * 256 + csw * 8;
  const u16* kbase  = qkv + (size_t)(b * 256 + sr) * C3 + 4096 + h * 256 + csw * 8;
  const u16* w2base = w2 + (size_t)head * 65536 + (size_t)sr * 256 + csw * 8;

  u16* lQ = Qs + t * 8;
  u16* lK = KVs + t * 8;

  const int fr = lane & 15;
  const int q  = lane >> 4;
  const int xk = fr & 7;
  const int er = q * 4;
  const int ec = fr;

  f32x4 acc[4][4] = {};

  const int kp = 2 * (qh + 1);   // staged K row-groups (32 rows each)

  // ---- Phase 1: S = Q @ K^T (K-dim = d = 256) ----
  for (int kt = 0; kt < 256; kt += BK) {
    async_load16(qbase + kt, lQ);
    async_load16(qbase + kt + 32 * C3, lQ + 2048);
    for (int p = 0; p < kp; ++p)
      async_load16(kbase + kt + (size_t)p * 32 * C3, lK + p * 2048);
    __syncthreads();
    if (wave <= qh) {
#pragma unroll
      for (int s = 0; s < 2; ++s) {
        const int ch = (((s << 2) | q) ^ xk) << 3;
        bf16x8 af[4], bfrag[4];
#pragma unroll
        for (int i = 0; i < 4; ++i)
          af[i] = *(const bf16x8*)(Qs + (i * 16 + fr) * BK + ch);
#pragma unroll
        for (int j = 0; j < 4; ++j)
          bfrag[j] = *(const bf16x8*)(KVs + (wn + j * 16 + fr) * BK + ch);
#pragma unroll
        for (int i = 0; i < 4; ++i)
#pragma unroll
          for (int j = 0; j < 4; ++j)
            acc[i][j] = __builtin_amdgcn_mfma_f32_16x16x32_bf16(af[i], bfrag[j], acc[i][j], 0, 0, 0);
      }
    }
    __syncthreads();
  }

  // epilogue 1: scale + causal + relu -> Ps[m][t_key] (only unmasked strips)
  if (wave <= qh) {
    const int qg0 = qh * 64;   // global q row of m=0
#pragma unroll
    for (int i = 0; i < 4; ++i)
#pragma unroll
      for (int j = 0; j < 4; ++j) {
        const int tk = wn + j * 16 + ec;   // key index
#pragma unroll
        for (int r = 0; r < 4; ++r) {
          const int m = i * 16 + er + r;
          float v = acc[i][j][r];
          v = (tk <= qg0 + m && v > 0.f) ? v * 0.0625f : 0.f;
          Ps[m * 264 + tk] = f32_to_bf16(v);
        }
      }
  }
  __syncthreads();

  // ---- Phase 2: Y = Ps @ W2t (kt only over unmasked key range) ----
#pragma unroll
  for (int i = 0; i < 4; ++i)
#pragma unroll
    for (int j = 0; j < 4; ++j)
      acc[i][j] = (f32x4){0.f, 0.f, 0.f, 0.f};

  const int nkt = (qh + 1) * 64;
  for (int kt = 0; kt < nkt; kt += BK) {
#pragma unroll
    for (int p = 0; p < 8; ++p)
      async_load16(w2base + kt + (size_t)p * 32 * 256, lK + p * 2048);
    __syncthreads();
#pragma unroll
    for (int s = 0; s < 2; ++s) {
      const int lo = kt + (((s << 2) | q) << 3);       // Ps: padded, no swizzle
      const int ch = (((s << 2) | q) ^ xk) << 3;       // KVs: swizzled
      bf16x8 af[4], bfrag[4];
#pragma unroll
      for (int i = 0; i < 4; ++i)
        af[i] = *(const bf16x8*)(Ps + (i * 16 + fr) * 264 + lo);
#pragma unroll
      for (int j = 0; j < 4; ++j)
        bfrag[j] = *(const bf16x8*)(KVs + (wn + j * 16 + fr) * BK + ch);
#pragma unroll
      for (int i = 0; i < 4; ++i)
#pragma unroll
        for (int j = 0; j < 4; ++j)
          acc[i][j] = __builtin_amdgcn_mfma_f32_16x16x32_bf16(af[i], bfrag[j], acc[i][j], 0, 0, 0);
    }
    __syncthreads();
  }

  // Y -> y[b*256+qh*64+m][h*256+d]
  {
    u16* yb = y + (size_t)(b * 256 + qh * 64) * 4096 + h * 256;
#pragma unroll
    for (int i = 0; i < 4; ++i)
#pragma unroll
      for (int j = 0; j < 4; ++j) {
        const int d = wn + j * 16 + ec;
#pragma unroll
        for (int r = 0; r < 4; ++r)
          yb[(size_t)(i * 16 + er + r) * 4096 + d] = f32_to_bf16(acc[i][j][r]);
      }
  }
}

// elementwise fp32 -> bf16, n multiple of 2048
__global__ __launch_bounds__(256) void cvt_f32_bf16(
    const float* __restrict__ in, u16* __restrict__ out, int64_t n)
{
  int64_t i = ((int64_t)blockIdx.x * 256 + threadIdx.x) * 8;
  if (i >= n) return;
  float4 a = *(const float4*)(in + i);
  float4 b = *(const float4*)(in + i + 4);
  union { u16 s[8]; uint4 v; } o;
  o.s[0] = f32_to_bf16(a.x); o.s[1] = f32_to_bf16(a.y);
  o.s[2] = f32_to_bf16(a.z); o.s[3] = f32_to_bf16(a.w);
  o.s[4] = f32_to_bf16(b.x); o.s[5] = f32_to_bf16(b.y);
  o.s[6] = f32_to_bf16(b.z); o.s[7] = f32_to_bf16(b.w);
  *(uint4*)(out + i) = o.v;
}

// out[c][r] = bf16(in[r][c]), in fp32. 64x64 tiles. Grid: (cols/64, rows/64, 1).
__global__ __launch_bounds__(256) void transpose_f32_bf16(
    const float* __restrict__ in, u16* __restrict__ out, int ldin, int ldout)
{
  __shared__ u16 tile[64][72];
  const int t = threadIdx.x;
  const int r0 = blockIdx.y * 64;
  const int c0 = blockIdx.x * 64;
  const int lr = t >> 3;
  const int lc = (t & 7) * 8;
#pragma unroll
  for (int p = 0; p < 2; ++p) {
    const int r = lr + p * 32;
    const float4 a = *(const float4*)(in + (size_t)(r0 + r) * ldin + c0 + lc);
    const float4 b = *(const float4*)(in + (size_t)(r0 + r) * ldin + c0 + lc + 4);
    union { u16 s[8]; uint4 v; } o;
    o.s[0] = f32_to_bf16(a.x); o.s[1] = f32_to_bf16(a.y);
    o.s[2] = f32_to_bf16(a.z); o.s[3] = f32_to_bf16(a.w);
    o.s[4] = f32_to_bf16(b.x); o.s[5] = f32_to_bf16(b.y);
    o.s[6] = f32_to_bf16(b.z); o.s[7] = f32_to_bf16(b.w);
    *(uint4*)&tile[r][lc] = o.v;
  }
  __syncthreads();
#pragma unroll
  for (int p = 0; p < 2; ++p) {
    const int c = (t >> 3) + p * 32;
    union { u16 s[8]; uint4 v; } buf;
#pragma unroll
    for (int i = 0; i < 8; ++i) buf.s[i] = tile[lc + i][c];
    *(uint4*)(out + (size_t)(c0 + c) * ldout + r0 + lc) = buf.v;
  }
}

// out[c][r] = in[r][c], bf16 -> bf16, batched. Grid: (cols/64, rows/64, batch).
__global__ __launch_bounds__(256) void transpose_bf16(
    const u16* __restrict__ in, u16* __restrict__ out, int ldin, int ldout,
    int64_t inOuter, int64_t inInner, int64_t outOuter, int64_t outInner)
{
  const int z = blockIdx.z;
  in  += (int64_t)(z >> 4) * inOuter  + (int64_t)(z & 15) * inInner;
  out += (int64_t)(z >> 4) * outOuter + (int64_t)(z & 15) * outInner;
  __shared__ u16 tile[64][72];
  const int t = threadIdx.x;
  const int r0 = blockIdx.y * 64;
  const int c0 = blockIdx.x * 64;
  const int lr = t >> 3;
  const int lc = (t & 7) * 8;
#pragma unroll
  for (int p = 0; p < 2; ++p) {
    const int r = lr + p * 32;
    const uint4 v = *(const uint4*)(in + (size_t)(r0 + r) * ldin + c0 + lc);
    *(uint4*)&tile[r][lc] = v;
  }
  __syncthreads();
#pragma unroll
  for (int p = 0; p < 2; ++p) {
    const int c = (t >> 3) + p * 32;
    union { u16 s[8]; uint4 v; } buf;
#pragma unroll
    for (int i = 0; i < 8; ++i) buf.s[i] = tile[lc + i][c];
    *(uint4*)(out + (size_t)(c0 + c) * ldout + r0 + lc) = buf.v;
  }
}

extern "C" void kernel_launch(void* const* d_in, const int* in_sizes, int n_in,
                              void* d_out, int out_size, void* d_ws, size_t ws_size,
                              hipStream_t stream) {
  const float* x      = (const float*)d_in[0];
  const float* W_attn = (const float*)d_in[1];
  const float* b_attn = (const float*)d_in[2];
  const float* W_proj = (const float*)d_in[3];
  const float* b_proj = (const float*)d_in[4];
  float* out = (float*)d_out;

  const int T = 256, Cd = 4096;
  const int BT = 4096;
  const int C3 = 12288;
  const int64_t headE = (int64_t)T * T;           // 65536
  const int64_t qkvE  = (int64_t)BT * C3;

  // ws overlay (u16 elems):
  //  [0, qkvE)        : qkv [4096,12288]
  //  [qkvE, 2*qkvE)   : Wt_attn (whole region, dead after step 3) ->
  //                     vt (32 MB) | Wt_proj (32 MB) | w2t (32 MB)
  //  [2*qkvE, ...)    : xb [4096,4096] -> later y
  u16* W0 = (u16*)d_ws;
  u16* qkv     = W0;
  u16* Wt_attn = W0 + qkvE;
  u16* vt      = W0 + qkvE;
  u16* Wt_proj = W0 + qkvE + 256 * headE;
  u16* w2t     = W0 + qkvE + 512 * headE;
  u16* xb      = W0 + 2 * qkvE;
  u16* y       = W0 + 2 * qkvE;

  dim3 blk(256);

  // 1. xb = bf16(x)
  cvt_f32_bf16<<<dim3((int)((int64_t)BT * Cd / 2048)), blk, 0, stream>>>(
      x, xb, (int64_t)BT * Cd);

  // 2. Wt_attn = bf16(W_attn^T)
  transpose_f32_bf16<<<dim3(C3 / 64, Cd / 64, 1), blk, 0, stream>>>(
      W_attn, Wt_attn, C3, Cd);

  // 3. qkv = xb @ W_attn + b_attn
  gemm_bt<<<dim3(C3 / BN, BT / BM, 1), blk, 0, stream>>>(
      xb, Wt_attn, qkv, b_attn, Cd, Cd, Cd, C3, 2, 0, 0, 0, 0, 0, 0);

  // 4. vt[z][d][t] = v[z][t][d]
  transpose_bf16<<<dim3(4, 4, 256), blk, 0, stream>>>(
      qkv + 2 * Cd, vt, C3, T,
      (int64_t)T * C3, (int64_t)T, 16 * headE, headE);

  // 5. w2t[head] = vt[head] @ V[head]^T  (= (V@V)^T), batched over 256 heads
  gemm_bt<<<dim3(2, 2, 256), blk, 0, stream>>>(
      vt, qkv + 2 * Cd, w2t, nullptr, 256, 256, C3, 256, 2,
      16 * headE, headE,                   // A: vt per-head
      (int64_t)256 * C3, (int64_t)256,     // B: V rows in qkv per (b,h)
      16 * headE, headE);                  // C: w2t per-head

  // 6. fused attention: P = relu(causal(QK^T/16)); y = P @ w2t
  attn_fused<<<dim3(1024), blk, 0, stream>>>(qkv, w2t, y);

  // 7. Wt_proj = bf16(W_proj^T)
  transpose_f32_bf16<<<dim3(Cd / 64, Cd / 64, 1), blk, 0, stream>>>(
      W_proj, Wt_proj, Cd, Cd);

  // 8. out = y @ W_proj + b_proj (fp32 store)
  gemm_bt<<<dim3(Cd / BN, BT / BM, 1), blk, 0, stream>>>(
      y, Wt_proj, out, b_proj, Cd, Cd, Cd, Cd, 3, 0, 0, 0, 0, 0, 0);
}

// Round 5
// 982.105 us; speedup vs baseline: 1.0556x; 1.0556x over previous
//
#include <hip/hip_runtime.h>
#include <stdint.h>

typedef unsigned short u16;
typedef __bf16 bf16x8 __attribute__((ext_vector_type(8)));
typedef float f32x4 __attribute__((ext_vector_type(4)));

__device__ inline u16 f32_to_bf16(float f) {
  union { float f; uint32_t u; } v; v.f = f;
  uint32_t u = v.u;
  u += 0x7FFF + ((u >> 16) & 1);   // round-to-nearest-even
  return (u16)(u >> 16);
}

__device__ inline void async_load16(const void* g, void* l) {
  __builtin_amdgcn_global_load_lds(
      (const __attribute__((address_space(1))) void*)g,
      (__attribute__((address_space(3))) void*)l, 16, 0, 0);
}

#define BM 128
#define BN 128
#define BK 64

// ============================================================================
// 256x256-tile GEMM (R2 code, verified passing twice; used for qkv + proj).
// C = A @ B^T. 512 threads, 8 waves, double-buffered 128 KiB LDS.
// ============================================================================
#define GBM 256
#define GBN 256

__global__ __launch_bounds__(512, 2) void gemm_bt_256(
    const u16* __restrict__ A, const u16* __restrict__ B, void* __restrict__ Cp,
    const float* __restrict__ bias, int K, int lda, int ldb, int ldc, int epi)
{
  __shared__ u16 As[32768];   // 2 bufs x 256 rows x 64 cols (64 KB)
  __shared__ u16 Bs[32768];   // 64 KB

  const int t = threadIdx.x;
  const int lane = t & 63;
  const int wave = t >> 6;
  const int wave_m = wave >> 2;   // 0..1
  const int wave_n = wave & 3;    // 0..3

  int bx = blockIdx.x, by = blockIdx.y;
  if ((gridDim.x & 7) == 0) {          // L2 super-tile swizzle
    int bid = by * gridDim.x + bx;
    int tig = gridDim.y << 3;
    int g = bid / tig;
    int l = bid - g * tig;
    bx = (g << 3) + (l & 7);
    by = l >> 3;
  }
  const int m0 = by * GBM;
  const int n0 = bx * GBN;

  // staging: thread t owns (row=t>>3 in 0..63, chunk=t&7); rounds at +64 rows
  const int sr = t >> 3;
  const int sc = t & 7;
  const int csw = sc ^ (sr & 7);
  const u16* gA = A + (size_t)(m0 + sr) * lda + csw * 8;
  const u16* gB = B + (size_t)(n0 + sr) * ldb + csw * 8;
  const size_t a64 = (size_t)64 * lda, b64 = (size_t)64 * ldb;
  const size_t a128 = a64 * 2, b128 = b64 * 2;
  u16* lA = As + t * 8;
  u16* lB = Bs + t * 8;

  const int fr = lane & 15;
  const int q  = lane >> 4;
  const int xk = fr & 7;
  const int wm16 = wave_m * 16;
  const int wn16 = wave_n * 16;

  f32x4 acc[8][4] = {};

  const int NT = K >> 6;

#define STAGE_A(buf, h, kt) do { \
    const u16* s_ = gA + (size_t)(h) * a128 + (kt); \
    u16* d_ = lA + ((buf) << 14) + ((h) << 13); \
    async_load16(s_, d_); \
    async_load16(s_ + a64, d_ + 4096); } while (0)
#define STAGE_B(buf, h, kt) do { \
    const u16* s_ = gB + (size_t)(h) * b128 + (kt); \
    u16* d_ = lB + ((buf) << 14) + ((h) << 13); \
    async_load16(s_, d_); \
    async_load16(s_ + b64, d_ + 4096); } while (0)

  // prologue: tile 0 (all 4 halves), then tile 1's A0, B1
  STAGE_A(0, 0, 0);
  STAGE_B(0, 0, 0);
  STAGE_B(0, 1, 0);
  STAGE_A(0, 1, 0);
  if (NT > 1) {
    STAGE_A(1, 0, BK);
    STAGE_B(1, 1, BK);
    asm volatile("s_waitcnt vmcnt(4)");
  } else {
    asm volatile("s_waitcnt vmcnt(0)");
  }
  __builtin_amdgcn_sched_barrier(0);
  __builtin_amdgcn_s_barrier();

  const int ch0 = (q ^ xk) << 3;        // k-slice 0 chunk (swizzled)
  const int ch1 = ((4 | q) ^ xk) << 3;  // k-slice 1 chunk

  for (int m = 0; m < NT; ++m) {
    const int buf = m & 1;
    const u16* Ab = As + (buf << 14);
    const u16* Bb = Bs + (buf << 14);
    const int kt1 = (m + 1) << 6;
    const int kt2 = (m + 2) << 6;
    const bool st1 = (m < NT - 1);
    const bool st2 = (m < NT - 2);

    bf16x8 af[4][2], bf[4][2];

    // ---- P1: (A-half0, B-half0) ----
#pragma unroll
    for (int f = 0; f < 4; ++f) {
      const u16* rp = Ab + (f * 32 + wm16 + fr) * 64;
      af[f][0] = *(const bf16x8*)(rp + ch0);
      af[f][1] = *(const bf16x8*)(rp + ch1);
    }
#pragma unroll
    for (int g = 0; g < 2; ++g) {
      const u16* rp = Bb + (g * 64 + wn16 + fr) * 64;
      bf[g][0] = *(const bf16x8*)(rp + ch0);
      bf[g][1] = *(const bf16x8*)(rp + ch1);
    }
    if (st1) STAGE_A(buf ^ 1, 1, kt1);
    __builtin_amdgcn_s_barrier();
    __builtin_amdgcn_s_setprio(1);
#pragma unroll
    for (int f = 0; f < 4; ++f)
#pragma unroll
      for (int g = 0; g < 2; ++g) {
        acc[f][g] = __builtin_amdgcn_mfma_f32_16x16x32_bf16(af[f][0], bf[g][0], acc[f][g], 0, 0, 0);
        acc[f][g] = __builtin_amdgcn_mfma_f32_16x16x32_bf16(af[f][1], bf[g][1], acc[f][g], 0, 0, 0);
      }
    __builtin_amdgcn_s_setprio(0);
    __builtin_amdgcn_s_barrier();

    // ---- P2: (A-half0, B-half1) ----
#pragma unroll
    for (int g = 2; g < 4; ++g) {
      const u16* rp = Bb + (g * 64 + wn16 + fr) * 64;
      bf[g][0] = *(const bf16x8*)(rp + ch0);
      bf[g][1] = *(const bf16x8*)(rp + ch1);
    }
    if (st1) STAGE_B(buf ^ 1, 0, kt1);
    __builtin_amdgcn_s_barrier();
    __builtin_amdgcn_s_setprio(1);
#pragma unroll
    for (int f = 0; f < 4; ++f)
#pragma unroll
      for (int g = 2; g < 4; ++g) {
        acc[f][g] = __builtin_amdgcn_mfma_f32_16x16x32_bf16(af[f][0], bf[g][0], acc[f][g], 0, 0, 0);
        acc[f][g] = __builtin_amdgcn_mfma_f32_16x16x32_bf16(af[f][1], bf[g][1], acc[f][g], 0, 0, 0);
      }
    __builtin_amdgcn_s_setprio(0);
    __builtin_amdgcn_s_barrier();

    // ---- P3: (A-half1, B-half1) ----
#pragma unroll
    for (int f = 0; f < 4; ++f) {
      const u16* rp = Ab + ((f + 4) * 32 + wm16 + fr) * 64;
      af[f][0] = *(const bf16x8*)(rp + ch0);
      af[f][1] = *(const bf16x8*)(rp + ch1);
    }
    if (st2) STAGE_A(buf, 0, kt2);
    __builtin_amdgcn_s_barrier();
    __builtin_amdgcn_s_setprio(1);
#pragma unroll
    for (int f = 0; f < 4; ++f)
#pragma unroll
      for (int g = 2; g < 4; ++g) {
        acc[f + 4][g] = __builtin_amdgcn_mfma_f32_16x16x32_bf16(af[f][0], bf[g][0], acc[f + 4][g], 0, 0, 0);
        acc[f + 4][g] = __builtin_amdgcn_mfma_f32_16x16x32_bf16(af[f][1], bf[g][1], acc[f + 4][g], 0, 0, 0);
      }
    __builtin_amdgcn_s_setprio(0);
    __builtin_amdgcn_s_barrier();

    // ---- P4: (A-half1, B-half0) ----  (bf[0..1] still live from P1)
    if (st2) STAGE_B(buf, 1, kt2);
    __builtin_amdgcn_s_barrier();
    __builtin_amdgcn_s_setprio(1);
#pragma unroll
    for (int f = 0; f < 4; ++f)
#pragma unroll
      for (int g = 0; g < 2; ++g) {
        acc[f + 4][g] = __builtin_amdgcn_mfma_f32_16x16x32_bf16(af[f][0], bf[g][0], acc[f + 4][g], 0, 0, 0);
        acc[f + 4][g] = __builtin_amdgcn_mfma_f32_16x16x32_bf16(af[f][1], bf[g][1], acc[f + 4][g], 0, 0, 0);
      }
    __builtin_amdgcn_s_setprio(0);
    // tile boundary: drain exactly through tile m+1's last half-tile
    if (st2)      asm volatile("s_waitcnt vmcnt(4)");
    else if (st1) asm volatile("s_waitcnt vmcnt(0)");
    __builtin_amdgcn_sched_barrier(0);
    __builtin_amdgcn_s_barrier();
  }

#undef STAGE_A
#undef STAGE_B

  // epilogue: C/D layout row = q*4 + r, col = fr within each 16x16 frag
  const int er = q << 2;
  u16* Cb = (u16*)Cp;
  float* Cf = (float*)Cp;
#pragma unroll
  for (int f = 0; f < 8; ++f) {
#pragma unroll
    for (int g = 0; g < 4; ++g) {
      const int n = n0 + g * 64 + wn16 + fr;
      const float bv = bias[n];
#pragma unroll
      for (int r = 0; r < 4; ++r) {
        const int mrow = m0 + f * 32 + wm16 + er + r;
        float v = acc[f][g][r] + bv;
        if (epi == 3) Cf[(size_t)mrow * ldc + n] = v;
        else          Cb[(size_t)mrow * ldc + n] = f32_to_bf16(v);
      }
    }
  }
}

// 128x128 GEMM, z-batched (kept for the small per-head w2t GEMM).
// C = A @ B^T. Offsets per z: zb = z>>4, zh = z&15.
__global__ __launch_bounds__(256, 2) void gemm_bt(
    const u16* __restrict__ A, const u16* __restrict__ B, void* __restrict__ Cp,
    const float* __restrict__ bias, int K, int lda, int ldb, int ldc, int epi,
    int64_t aO, int64_t aI, int64_t bO, int64_t bI, int64_t cO, int64_t cI)
{
  __shared__ u16 As[BM * BK];   // 16 KB
  __shared__ u16 Bs[BN * BK];   // 16 KB

  const int t = threadIdx.x;
  const int lane = t & 63;
  const int wave = t >> 6;

  const int zb = blockIdx.z >> 4, zh = blockIdx.z & 15;
  A += zb * aO + zh * aI;
  B += zb * bO + zh * bI;
  u16*   Cb = (u16*)Cp + zb * cO + zh * cI;
  float* Cf = (float*)Cp + zb * cO + zh * cI;

  int bx = blockIdx.x, by = blockIdx.y;
  if ((gridDim.x & 7) == 0) {          // L2 super-tile swizzle
    int bid = by * gridDim.x + bx;
    int tig = gridDim.y << 3;
    int g = bid / tig;
    int l = bid - g * tig;
    bx = (g << 3) + (l & 7);
    by = l >> 3;
  }
  const int m0 = by * BM;
  const int n0 = bx * BN;
  const int wm = (wave >> 1) * 64;
  const int wn = (wave & 1) * 64;

  const int sr = t >> 3;
  const int sc = t & 7;
  const int csw = sc ^ (sr & 7);
  const u16* ga = A + (size_t)(m0 + sr) * lda + csw * 8;
  const u16* gb = B + (size_t)(n0 + sr) * ldb + csw * 8;
  const size_t a32 = (size_t)32 * lda;
  const size_t b32 = (size_t)32 * ldb;
  u16* lA = As + t * 8;
  u16* lB = Bs + t * 8;

  f32x4 acc[4][4] = {};

  const int fr = lane & 15;
  const int q  = lane >> 4;
  const int xk = fr & 7;

  for (int kt = 0; kt < K; kt += BK) {
    async_load16(ga,            lA);
    async_load16(ga +     a32,  lA + 2048);
    async_load16(ga + 2 * a32,  lA + 4096);
    async_load16(ga + 3 * a32,  lA + 6144);
    async_load16(gb,            lB);
    async_load16(gb +     b32,  lB + 2048);
    async_load16(gb + 2 * b32,  lB + 4096);
    async_load16(gb + 3 * b32,  lB + 6144);
    ga += BK; gb += BK;
    __syncthreads();

#pragma unroll
    for (int s = 0; s < 2; ++s) {
      const int ch = (((s << 2) | q) ^ xk) << 3;
      bf16x8 af[4], bfrag[4];
#pragma unroll
      for (int i = 0; i < 4; ++i)
        af[i] = *(const bf16x8*)(As + (wm + i * 16 + fr) * BK + ch);
#pragma unroll
      for (int j = 0; j < 4; ++j)
        bfrag[j] = *(const bf16x8*)(Bs + (wn + j * 16 + fr) * BK + ch);
#pragma unroll
      for (int i = 0; i < 4; ++i)
#pragma unroll
        for (int j = 0; j < 4; ++j)
          acc[i][j] = __builtin_amdgcn_mfma_f32_16x16x32_bf16(af[i], bfrag[j], acc[i][j], 0, 0, 0);
    }
    __syncthreads();
  }

  const int er = (lane >> 4) * 4;
  const int ec = lane & 15;
#pragma unroll
  for (int i = 0; i < 4; ++i) {
#pragma unroll
    for (int j = 0; j < 4; ++j) {
      const int n = n0 + wn + j * 16 + ec;
      const float bv = bias ? bias[n] : 0.0f;
#pragma unroll
      for (int r = 0; r < 4; ++r) {
        const int m = m0 + wm + i * 16 + er + r;
        float v = acc[i][j][r] + bv;
        if (epi == 3) Cf[(size_t)m * ldc + n] = v;
        else          Cb[(size_t)m * ldc + n] = f32_to_bf16(v);
      }
    }
  }
}

// Fused attention (R4, verified): Y = P @ W2t, W2t = (V@V)^T per head.
// Causal work-skipping: quarter qh needs keys < (qh+1)*64 only.
__global__ __launch_bounds__(256, 2) void attn_fused(
    const u16* __restrict__ qkv, const u16* __restrict__ w2,
    u16* __restrict__ y)
{
  const int head = blockIdx.x >> 2;    // 0..255
  const int qh   = blockIdx.x & 3;     // q quarter
  const int b    = head >> 4;
  const int h    = head & 15;
  const int C3 = 12288;

  __shared__ u16 Ps[64 * 264];
  __shared__ u16 Qs[64 * 64];
  __shared__ u16 KVs[256 * 64];

  const int t = threadIdx.x;
  const int lane = t & 63;
  const int wave = t >> 6;
  const int wn = wave * 64;

  const int sr = t >> 3;
  const int sc = t & 7;
  const int csw = sc ^ (sr & 7);

  const u16* qbase  = qkv + (size_t)(b * 256 + qh * 64 + sr) * C3 + h * 256 + csw * 8;
  const u16* kbase  = qkv + (size_t)(b * 256 + sr) * C3 + 4096 + h * 256 + csw * 8;
  const u16* w2base = w2 + (size_t)head * 65536 + (size_t)sr * 256 + csw * 8;

  u16* lQ = Qs + t * 8;
  u16* lK = KVs + t * 8;

  const int fr = lane & 15;
  const int q  = lane >> 4;
  const int xk = fr & 7;
  const int er = q * 4;
  const int ec = fr;

  f32x4 acc[4][4] = {};

  const int kp = 2 * (qh + 1);   // staged K row-groups (32 rows each)

  // ---- Phase 1: S = Q @ K^T (K-dim = d = 256) ----
  for (int kt = 0; kt < 256; kt += BK) {
    async_load16(qbase + kt, lQ);
    async_load16(qbase + kt + 32 * C3, lQ + 2048);
    for (int p = 0; p < kp; ++p)
      async_load16(kbase + kt + (size_t)p * 32 * C3, lK + p * 2048);
    __syncthreads();
    if (wave <= qh) {
#pragma unroll
      for (int s = 0; s < 2; ++s) {
        const int ch = (((s << 2) | q) ^ xk) << 3;
        bf16x8 af[4], bfrag[4];
#pragma unroll
        for (int i = 0; i < 4; ++i)
          af[i] = *(const bf16x8*)(Qs + (i * 16 + fr) * BK + ch);
#pragma unroll
        for (int j = 0; j < 4; ++j)
          bfrag[j] = *(const bf16x8*)(KVs + (wn + j * 16 + fr) * BK + ch);
#pragma unroll
        for (int i = 0; i < 4; ++i)
#pragma unroll
          for (int j = 0; j < 4; ++j)
            acc[i][j] = __builtin_amdgcn_mfma_f32_16x16x32_bf16(af[i], bfrag[j], acc[i][j], 0, 0, 0);
      }
    }
    __syncthreads();
  }

  // epilogue 1: scale + causal + relu -> Ps[m][t_key]
  if (wave <= qh) {
    const int qg0 = qh * 64;
#pragma unroll
    for (int i = 0; i < 4; ++i)
#pragma unroll
      for (int j = 0; j < 4; ++j) {
        const int tk = wn + j * 16 + ec;
#pragma unroll
        for (int r = 0; r < 4; ++r) {
          const int m = i * 16 + er + r;
          float v = acc[i][j][r];
          v = (tk <= qg0 + m && v > 0.f) ? v * 0.0625f : 0.f;
          Ps[m * 264 + tk] = f32_to_bf16(v);
        }
      }
  }
  __syncthreads();

  // ---- Phase 2: Y = Ps @ W2t (kt only over unmasked key range) ----
#pragma unroll
  for (int i = 0; i < 4; ++i)
#pragma unroll
    for (int j = 0; j < 4; ++j)
      acc[i][j] = (f32x4){0.f, 0.f, 0.f, 0.f};

  const int nkt = (qh + 1) * 64;
  for (int kt = 0; kt < nkt; kt += BK) {
#pragma unroll
    for (int p = 0; p < 8; ++p)
      async_load16(w2base + kt + (size_t)p * 32 * 256, lK + p * 2048);
    __syncthreads();
#pragma unroll
    for (int s = 0; s < 2; ++s) {
      const int lo = kt + (((s << 2) | q) << 3);
      const int ch = (((s << 2) | q) ^ xk) << 3;
      bf16x8 af[4], bfrag[4];
#pragma unroll
      for (int i = 0; i < 4; ++i)
        af[i] = *(const bf16x8*)(Ps + (i * 16 + fr) * 264 + lo);
#pragma unroll
      for (int j = 0; j < 4; ++j)
        bfrag[j] = *(const bf16x8*)(KVs + (wn + j * 16 + fr) * BK + ch);
#pragma unroll
      for (int i = 0; i < 4; ++i)
#pragma unroll
        for (int j = 0; j < 4; ++j)
          acc[i][j] = __builtin_amdgcn_mfma_f32_16x16x32_bf16(af[i], bfrag[j], acc[i][j], 0, 0, 0);
    }
    __syncthreads();
  }

  {
    u16* yb = y + (size_t)(b * 256 + qh * 64) * 4096 + h * 256;
#pragma unroll
    for (int i = 0; i < 4; ++i)
#pragma unroll
      for (int j = 0; j < 4; ++j) {
        const int d = wn + j * 16 + ec;
#pragma unroll
        for (int r = 0; r < 4; ++r)
          yb[(size_t)(i * 16 + er + r) * 4096 + d] = f32_to_bf16(acc[i][j][r]);
      }
  }
}

// elementwise fp32 -> bf16, n multiple of 2048
__global__ __launch_bounds__(256) void cvt_f32_bf16(
    const float* __restrict__ in, u16* __restrict__ out, int64_t n)
{
  int64_t i = ((int64_t)blockIdx.x * 256 + threadIdx.x) * 8;
  if (i >= n) return;
  float4 a = *(const float4*)(in + i);
  float4 b = *(const float4*)(in + i + 4);
  union { u16 s[8]; uint4 v; } o;
  o.s[0] = f32_to_bf16(a.x); o.s[1] = f32_to_bf16(a.y);
  o.s[2] = f32_to_bf16(a.z); o.s[3] = f32_to_bf16(a.w);
  o.s[4] = f32_to_bf16(b.x); o.s[5] = f32_to_bf16(b.y);
  o.s[6] = f32_to_bf16(b.z); o.s[7] = f32_to_bf16(b.w);
  *(uint4*)(out + i) = o.v;
}

// out[c][r] = bf16(in[r][c]), in fp32. 64x64 tiles. Grid: (cols/64, rows/64, 1).
__global__ __launch_bounds__(256) void transpose_f32_bf16(
    const float* __restrict__ in, u16* __restrict__ out, int ldin, int ldout)
{
  __shared__ u16 tile[64][72];
  const int t = threadIdx.x;
  const int r0 = blockIdx.y * 64;
  const int c0 = blockIdx.x * 64;
  const int lr = t >> 3;
  const int lc = (t & 7) * 8;
#pragma unroll
  for (int p = 0; p < 2; ++p) {
    const int r = lr + p * 32;
    const float4 a = *(const float4*)(in + (size_t)(r0 + r) * ldin + c0 + lc);
    const float4 b = *(const float4*)(in + (size_t)(r0 + r) * ldin + c0 + lc + 4);
    union { u16 s[8]; uint4 v; } o;
    o.s[0] = f32_to_bf16(a.x); o.s[1] = f32_to_bf16(a.y);
    o.s[2] = f32_to_bf16(a.z); o.s[3] = f32_to_bf16(a.w);
    o.s[4] = f32_to_bf16(b.x); o.s[5] = f32_to_bf16(b.y);
    o.s[6] = f32_to_bf16(b.z); o.s[7] = f32_to_bf16(b.w);
    *(uint4*)&tile[r][lc] = o.v;
  }
  __syncthreads();
#pragma unroll
  for (int p = 0; p < 2; ++p) {
    const int c = (t >> 3) + p * 32;
    union { u16 s[8]; uint4 v; } buf;
#pragma unroll
    for (int i = 0; i < 8; ++i) buf.s[i] = tile[lc + i][c];
    *(uint4*)(out + (size_t)(c0 + c) * ldout + r0 + lc) = buf.v;
  }
}

// out[c][r] = in[r][c], bf16 -> bf16, batched. Grid: (cols/64, rows/64, batch).
__global__ __launch_bounds__(256) void transpose_bf16(
    const u16* __restrict__ in, u16* __restrict__ out, int ldin, int ldout,
    int64_t inOuter, int64_t inInner, int64_t outOuter, int64_t outInner)
{
  const int z = blockIdx.z;
  in  += (int64_t)(z >> 4) * inOuter  + (int64_t)(z & 15) * inInner;
  out += (int64_t)(z >> 4) * outOuter + (int64_t)(z & 15) * outInner;
  __shared__ u16 tile[64][72];
  const int t = threadIdx.x;
  const int r0 = blockIdx.y * 64;
  const int c0 = blockIdx.x * 64;
  const int lr = t >> 3;
  const int lc = (t & 7) * 8;
#pragma unroll
  for (int p = 0; p < 2; ++p) {
    const int r = lr + p * 32;
    const uint4 v = *(const uint4*)(in + (size_t)(r0 + r) * ldin + c0 + lc);
    *(uint4*)&tile[r][lc] = v;
  }
  __syncthreads();
#pragma unroll
  for (int p = 0; p < 2; ++p) {
    const int c = (t >> 3) + p * 32;
    union { u16 s[8]; uint4 v; } buf;
#pragma unroll
    for (int i = 0; i < 8; ++i) buf.s[i] = tile[lc + i][c];
    *(uint4*)(out + (size_t)(c0 + c) * ldout + r0 + lc) = buf.v;
  }
}

extern "C" void kernel_launch(void* const* d_in, const int* in_sizes, int n_in,
                              void* d_out, int out_size, void* d_ws, size_t ws_size,
                              hipStream_t stream) {
  const float* x      = (const float*)d_in[0];
  const float* W_attn = (const float*)d_in[1];
  const float* b_attn = (const float*)d_in[2];
  const float* W_proj = (const float*)d_in[3];
  const float* b_proj = (const float*)d_in[4];
  float* out = (float*)d_out;

  const int T = 256, Cd = 4096;
  const int BT = 4096;
  const int C3 = 12288;
  const int64_t headE = (int64_t)T * T;           // 65536
  const int64_t qkvE  = (int64_t)BT * C3;

  // ws overlay (u16 elems):
  //  [0, qkvE)        : qkv [4096,12288]
  //  [qkvE, 2*qkvE)   : Wt_attn (dead after step 3) -> vt | Wt_proj | w2t
  //  [2*qkvE, ...)    : xb [4096,4096] -> later y
  u16* W0 = (u16*)d_ws;
  u16* qkv     = W0;
  u16* Wt_attn = W0 + qkvE;
  u16* vt      = W0 + qkvE;
  u16* Wt_proj = W0 + qkvE + 256 * headE;
  u16* w2t     = W0 + qkvE + 512 * headE;
  u16* xb      = W0 + 2 * qkvE;
  u16* y       = W0 + 2 * qkvE;

  dim3 blk(256);
  dim3 blk512(512);

  // 1. xb = bf16(x)
  cvt_f32_bf16<<<dim3((int)((int64_t)BT * Cd / 2048)), blk, 0, stream>>>(
      x, xb, (int64_t)BT * Cd);

  // 2. Wt_attn = bf16(W_attn^T)
  transpose_f32_bf16<<<dim3(C3 / 64, Cd / 64, 1), blk, 0, stream>>>(
      W_attn, Wt_attn, C3, Cd);

  // 3. qkv = xb @ W_attn + b_attn — SPLIT into 3 N=4096 dispatches
  //    (diagnostic: makes any hidden dispatch >~145 us visible in top-5)
  for (int p = 0; p < 3; ++p) {
    gemm_bt_256<<<dim3(Cd / GBN, BT / GBM, 1), blk512, 0, stream>>>(
        xb, Wt_attn + (size_t)p * Cd * Cd, qkv + p * Cd, b_attn + p * Cd,
        Cd, Cd, Cd, C3, 2);
  }

  // 4. vt[z][d][t] = v[z][t][d]
  transpose_bf16<<<dim3(4, 4, 256), blk, 0, stream>>>(
      qkv + 2 * Cd, vt, C3, T,
      (int64_t)T * C3, (int64_t)T, 16 * headE, headE);

  // 5. w2t[head] = vt[head] @ V[head]^T  (= (V@V)^T), batched over 256 heads
  gemm_bt<<<dim3(2, 2, 256), blk, 0, stream>>>(
      vt, qkv + 2 * Cd, w2t, nullptr, 256, 256, C3, 256, 2,
      16 * headE, headE,
      (int64_t)256 * C3, (int64_t)256,
      16 * headE, headE);

  // 6. fused attention: P = relu(causal(QK^T/16)); y = P @ w2t
  attn_fused<<<dim3(1024), blk, 0, stream>>>(qkv, w2t, y);

  // 7. Wt_proj = bf16(W_proj^T)
  transpose_f32_bf16<<<dim3(Cd / 64, Cd / 64, 1), blk, 0, stream>>>(
      W_proj, Wt_proj, Cd, Cd);

  // 8. out = y @ W_proj + b_proj (fp32 store, 256x256)
  gemm_bt_256<<<dim3(Cd / GBN, BT / GBM, 1), blk512, 0, stream>>>(
      y, Wt_proj, out, b_proj, Cd, Cd, Cd, Cd, 3);
}